// Round 6
// baseline (512.769 us; speedup 1.0000x reference)
//
#include <hip/hip_runtime.h>
#include <math.h>

#define B_  2
#define T_  2048
#define D_  2048
#define H_  16
#define DH  128
#define BT  (B_ * T_)          // 4096 rows

typedef float    f32x4 __attribute__((ext_vector_type(4)));
typedef _Float16 f16x8 __attribute__((ext_vector_type(8)));
typedef __fp16   fp16x2 __attribute__((ext_vector_type(2)));

typedef __attribute__((address_space(1))) const void* gas_t;
typedef __attribute__((address_space(3))) void*       las_t;

__device__ __forceinline__ void gll16(const void* g, void* l) {
    __builtin_amdgcn_global_load_lds((gas_t)g, (las_t)l, 16, 0, 0);
}

__device__ __forceinline__ unsigned short h16bits(float f) {
    union { _Float16 h; unsigned short u; } c; c.h = (_Float16)f; return c.u;
}
// pack 2 fp32 -> 2 fp16 (RTZ) in one v_cvt_pkrtz_f16_f32
__device__ __forceinline__ unsigned pk2h(float a, float b) {
    union { fp16x2 h; unsigned u; } c;
    c.h = __builtin_amdgcn_cvt_pkrtz(a, b);
    return c.u;
}

// ---------------------------------------------------------------------------
// fp32 -> fp16 conversion, 4 segments in one launch (blockIdx.y = segment)
// ---------------------------------------------------------------------------
__global__ __launch_bounds__(256)
void f32_to_f16_multi(const float* __restrict__ s0, _Float16* __restrict__ d0, int n0,
                      const float* __restrict__ s1, _Float16* __restrict__ d1, int n1,
                      const float* __restrict__ s2, _Float16* __restrict__ d2, int n2,
                      const float* __restrict__ s3, _Float16* __restrict__ d3, int n3) {
    const float* s; _Float16* d; int n;
    switch (blockIdx.y) {
        case 0:  s = s0; d = d0; n = n0; break;
        case 1:  s = s1; d = d1; n = n1; break;
        case 2:  s = s2; d = d2; n = n2; break;
        default: s = s3; d = d3; n = n3; break;
    }
    int i = blockIdx.x * 256 + threadIdx.x;
    if (i >= n) return;
    const float4 a = *(const float4*)(s + (size_t)i * 8);
    const float4 b = *(const float4*)(s + (size_t)i * 8 + 4);
    f16x8 o;
    o[0] = (_Float16)a.x; o[1] = (_Float16)a.y; o[2] = (_Float16)a.z; o[3] = (_Float16)a.w;
    o[4] = (_Float16)b.x; o[5] = (_Float16)b.y; o[6] = (_Float16)b.z; o[7] = (_Float16)b.w;
    *(f16x8*)(d + (size_t)i * 8) = o;
}

__global__ __launch_bounds__(256)
void f32_to_f16(const float* __restrict__ in, _Float16* __restrict__ out, int n8) {
    int i = blockIdx.x * 256 + threadIdx.x;
    if (i >= n8) return;
    const float4 a = *(const float4*)(in + (size_t)i * 8);
    const float4 b = *(const float4*)(in + (size_t)i * 8 + 4);
    f16x8 o;
    o[0] = (_Float16)a.x; o[1] = (_Float16)a.y; o[2] = (_Float16)a.z; o[3] = (_Float16)a.w;
    o[4] = (_Float16)b.x; o[5] = (_Float16)b.y; o[6] = (_Float16)b.z; o[7] = (_Float16)b.w;
    *(f16x8*)(out + (size_t)i * 8) = o;
}

// ---------------------------------------------------------------------------
// fp16 MFMA GEMM (m97 structure): C = A @ W^T. A,W fp16 planes.
// 128x128 tile, BK=64, 4 waves, global_load_lds(16B) staging, XOR-swizzled
// LDS via pre-permuted global source granules + linear LDS dest.
// EPI: 0 = fp32 C, 1 = fp16 C, 2 = transposed fp16 Vt[(b*D+n)*T + t].
// ---------------------------------------------------------------------------
#define BKK 64

template<int EPI>
__global__ __launch_bounds__(256, 3)
void gemm16(const _Float16* __restrict__ Ag, const _Float16* __restrict__ Bg,
            float* __restrict__ Cf, _Float16* __restrict__ C16,
            _Float16* __restrict__ Vt, int M, int N, int K) {
    __shared__ _Float16 As[128 * BKK];
    __shared__ _Float16 Bs[128 * BKK];

    const int tid  = threadIdx.x;
    const int lane = tid & 63;
    const int w    = tid >> 6;
    const int wr   = w >> 1, wc = w & 1;
    const int c    = lane & 15, g = lane >> 4;

    const int nwg = gridDim.x;
    const int bid = blockIdx.x;
    const int swz = (bid & 7) * (nwg >> 3) + (bid >> 3);
    const int nb  = N / 128;
    const int bm  = (swz / nb) * 128;
    const int bn  = (swz % nb) * 128;

    const int srow = tid >> 3;                       // 0..31 (+ i*32)
    const int sg   = (tid & 7) ^ (srow & 7);         // pre-permuted source granule
    const _Float16* Ab = Ag + (size_t)(bm + srow) * K + sg * 8;
    const _Float16* Bb = Bg + (size_t)(bn + srow) * K + sg * 8;

    f32x4 acc[4][4];
    #pragma unroll
    for (int mi = 0; mi < 4; ++mi)
        #pragma unroll
        for (int ni = 0; ni < 4; ++ni)
            #pragma unroll
            for (int r = 0; r < 4; ++r) acc[mi][ni][r] = 0.f;

    for (int k0 = 0; k0 < K; k0 += BKK) {
        __syncthreads();
        #pragma unroll
        for (int i = 0; i < 4; ++i) {
            gll16(Ab + (size_t)i * 32 * K + k0, &As[(i * 256 + tid) * 8]);
            gll16(Bb + (size_t)i * 32 * K + k0, &Bs[(i * 256 + tid) * 8]);
        }
        __syncthreads();

        #pragma unroll
        for (int kc = 0; kc < 2; ++kc) {
            f16x8 fa[4], fb[4];
            #pragma unroll
            for (int mi = 0; mi < 4; ++mi) {
                const int row = wr * 64 + mi * 16 + c;
                fa[mi] = *(const f16x8*)&As[row * 64 + (((kc * 4 + g) ^ (c & 7)) * 8)];
            }
            #pragma unroll
            for (int ni = 0; ni < 4; ++ni) {
                const int row = wc * 64 + ni * 16 + c;
                fb[ni] = *(const f16x8*)&Bs[row * 64 + (((kc * 4 + g) ^ (c & 7)) * 8)];
            }
            #pragma unroll
            for (int mi = 0; mi < 4; ++mi)
                #pragma unroll
                for (int ni = 0; ni < 4; ++ni)
                    acc[mi][ni] = __builtin_amdgcn_mfma_f32_16x16x32_f16(fa[mi], fb[ni], acc[mi][ni], 0, 0, 0);
        }
    }

    #pragma unroll
    for (int mi = 0; mi < 4; ++mi) {
        #pragma unroll
        for (int ni = 0; ni < 4; ++ni) {
            const int m0 = bm + wr * 64 + mi * 16 + g * 4;
            const int n  = bn + wc * 64 + ni * 16 + c;
            if constexpr (EPI == 0) {
                #pragma unroll
                for (int r = 0; r < 4; ++r)
                    Cf[(size_t)(m0 + r) * N + n] = acc[mi][ni][r];
            } else if constexpr (EPI == 1) {
                #pragma unroll
                for (int r = 0; r < 4; ++r)
                    C16[(size_t)(m0 + r) * N + n] = (_Float16)acc[mi][ni][r];
            } else {
                const int bb = m0 >> 11, t = m0 & (T_ - 1);
                ushort4 o;
                o.x = h16bits(acc[mi][ni][0]); o.y = h16bits(acc[mi][ni][1]);
                o.z = h16bits(acc[mi][ni][2]); o.w = h16bits(acc[mi][ni][3]);
                *(ushort4*)&Vt[((size_t)bb * D_ + n) * T_ + t] = o;
            }
        }
    }
}

// ---------------------------------------------------------------------------
// Flash-style differential attention, fp16, 8 waves / 128 q-rows per block,
// double-buffered gll staging, exp2-domain softmax, defer-max (THR=8 in lb2).
// ---------------------------------------------------------------------------
__device__ __forceinline__ void softmax_upd(f32x4 s[4], f32x4 O[8],
                                            float& m, float& l,
                                            unsigned pk[4][2], int g) {
    const float C1 = 0.125f * 1.44269504089f;   // log2(e)/sqrt(64)
    float tmax = -1e30f;
    #pragma unroll
    for (int mt = 0; mt < 4; ++mt)
        #pragma unroll
        for (int r = 0; r < 4; ++r) {
            s[mt][r] *= C1;                      // scores in exp2 domain
            tmax = fmaxf(tmax, s[mt][r]);
        }
    tmax = fmaxf(tmax, __shfl_xor(tmax, 16));
    tmax = fmaxf(tmax, __shfl_xor(tmax, 32));
    if (!__all(tmax <= m + 8.f)) {               // rescale path (rare)
        float mnew = fmaxf(m, tmax);
        float al   = exp2f(m - mnew);
        #pragma unroll
        for (int r = 0; r < 4; ++r) {
            float alr = __shfl(al, (g << 2) | r);
            #pragma unroll
            for (int nt = 0; nt < 8; ++nt) O[nt][r] *= alr;
        }
        l *= al;
        m  = mnew;
    }
    float tsum = 0.f;
    #pragma unroll
    for (int mt = 0; mt < 4; ++mt)
        #pragma unroll
        for (int r = 0; r < 4; ++r) {
            float p = exp2f(s[mt][r] - m);       // bounded by 2^8
            s[mt][r] = p; tsum += p;
        }
    tsum += __shfl_xor(tsum, 16);
    tsum += __shfl_xor(tsum, 32);
    l += tsum;
    #pragma unroll
    for (int mt = 0; mt < 4; ++mt) {
        pk[mt][0] = pk2h(s[mt][0], s[mt][1]);
        pk[mt][1] = pk2h(s[mt][2], s[mt][3]);
    }
}

__global__ __launch_bounds__(512, 4)
void diff_attn_f16(_Float16* Qh,
                   const _Float16* __restrict__ Kh,
                   const _Float16* __restrict__ Vt,
                   const float* __restrict__ lambda_param) {
    __shared__ _Float16 k_s[2][64 * 128];
    __shared__ _Float16 v_s[2][128 * 64];

    const int tid  = threadIdx.x;
    const int lane = tid & 63;
    const int w    = tid >> 6;                   // 0..7
    const int b    = blockIdx.z, h = blockIdx.y;
    const int t0   = blockIdx.x * 128;
    const int c    = lane & 15;
    const int g    = lane >> 4;

    const float lam = 1.f / (1.f + __expf(-lambda_param[h]));

    // ---- Q fragments (fp16 plane; scale folded into softmax)
    const int q0 = t0 + w * 16;
    const _Float16* Qg = Qh + (size_t)(b * T_ + q0 + c) * D_ + h * DH;
    f16x8 qf[4];
    #pragma unroll
    for (int kb = 0; kb < 4; ++kb)
        qf[kb] = *(const f16x8*)&Qg[kb * 32 + g * 8];

    f32x4 O1[8], O2[8];
    #pragma unroll
    for (int nt = 0; nt < 8; ++nt)
        #pragma unroll
        for (int r = 0; r < 4; ++r) { O1[nt][r] = 0.f; O2[nt][r] = 0.f; }
    float m1 = -1e30f, l1 = 0.f, m2 = -1e30f, l2 = 0.f;

    // staging geometry (512 threads; lane-linear LDS dests for gll)
    const int kkey = tid >> 4;                   // 0..31 (+ i*32)
    const int kgs  = (tid & 15) ^ (kkey & 7);
    const int vd   = tid >> 3;                   // 0..63 (+ i*64)
    const int vgs  = (tid & 7) ^ (vd & 7);
    const size_t rowK = (size_t)(b * T_);
    const size_t rowV = (size_t)(b * D_ + h * DH);

    auto STAGE = [&](int s0, int buf) {
        #pragma unroll
        for (int i = 0; i < 2; ++i) {
            const size_t goff = (rowK + s0 + i * 32 + kkey) * (size_t)D_ + h * DH + kgs * 8;
            gll16(&Kh[goff], &k_s[buf][(i * 512 + tid) * 8]);
        }
        #pragma unroll
        for (int i = 0; i < 2; ++i) {
            const size_t goff = (rowV + i * 64 + vd) * (size_t)T_ + s0 + vgs * 8;
            gll16(&Vt[goff], &v_s[buf][(i * 512 + tid) * 8]);
        }
    };

    STAGE(0, 0);
    __syncthreads();                             // tile 0 ready

    const int NT = T_ / 64;
    for (int t = 0; t < NT; ++t) {
        const int cur = t & 1;
        if (t + 1 < NT) STAGE((t + 1) * 64, cur ^ 1);

        // ---- QK^T (S^T tiles): A = K (LDS), B = Q (regs)
        f32x4 s1[4], s2[4];
        #pragma unroll
        for (int mt = 0; mt < 4; ++mt)
            #pragma unroll
            for (int r = 0; r < 4; ++r) { s1[mt][r] = 0.f; s2[mt][r] = 0.f; }
        __builtin_amdgcn_s_setprio(1);
        #pragma unroll
        for (int mt = 0; mt < 4; ++mt) {
            const int key  = mt * 16 + c;
            const int krow = key * 128;
            #pragma unroll
            for (int kb = 0; kb < 4; ++kb) {
                const int gp = ((4 * kb + g) ^ (key & 7)) * 8;
                f16x8 kf = *(const f16x8*)&k_s[cur][krow + gp];
                if (kb < 2) s1[mt] = __builtin_amdgcn_mfma_f32_16x16x32_f16(kf, qf[kb], s1[mt], 0, 0, 0);
                else        s2[mt] = __builtin_amdgcn_mfma_f32_16x16x32_f16(kf, qf[kb], s2[mt], 0, 0, 0);
            }
        }
        __builtin_amdgcn_s_setprio(0);

        unsigned pk1[4][2], pk2v[4][2];
        softmax_upd(s1, O1, m1, l1, pk1,  g);
        softmax_upd(s2, O2, m2, l2, pk2v, g);

        // ---- PV: A = P (shuffled to A-layout), B = V fragments
        const int srcA = ((2 * (g & 1)) << 4) | c;
        const int srcB = ((2 * (g & 1) + 1) << 4) | c;
        const bool hiSel = (g & 2) != 0;
        #pragma unroll
        for (int kb = 0; kb < 2; ++kb) {
            f16x8 vf[8];
            #pragma unroll
            for (int nt = 0; nt < 8; ++nt) {
                const int d  = nt * 16 + c;
                const int gp = ((4 * kb + g) ^ (d & 7)) * 8;
                vf[nt] = *(const f16x8*)&v_s[cur][d * 64 + gp];
            }
            unsigned u00 = (unsigned)__shfl((int)pk1[2 * kb][0], srcA);
            unsigned u10 = (unsigned)__shfl((int)pk1[2 * kb + 1][0], srcA);
            unsigned u01 = (unsigned)__shfl((int)pk1[2 * kb][1], srcA);
            unsigned u11 = (unsigned)__shfl((int)pk1[2 * kb + 1][1], srcA);
            unsigned u02 = (unsigned)__shfl((int)pk1[2 * kb][0], srcB);
            unsigned u12 = (unsigned)__shfl((int)pk1[2 * kb + 1][0], srcB);
            unsigned u03 = (unsigned)__shfl((int)pk1[2 * kb][1], srcB);
            unsigned u13 = (unsigned)__shfl((int)pk1[2 * kb + 1][1], srcB);
            union { unsigned u[4]; f16x8 v; } pa1;
            pa1.u[0] = hiSel ? u10 : u00;
            pa1.u[1] = hiSel ? u11 : u01;
            pa1.u[2] = hiSel ? u12 : u02;
            pa1.u[3] = hiSel ? u13 : u03;
            unsigned w00 = (unsigned)__shfl((int)pk2v[2 * kb][0], srcA);
            unsigned w10 = (unsigned)__shfl((int)pk2v[2 * kb + 1][0], srcA);
            unsigned w01 = (unsigned)__shfl((int)pk2v[2 * kb][1], srcA);
            unsigned w11 = (unsigned)__shfl((int)pk2v[2 * kb + 1][1], srcA);
            unsigned w02 = (unsigned)__shfl((int)pk2v[2 * kb][0], srcB);
            unsigned w12 = (unsigned)__shfl((int)pk2v[2 * kb + 1][0], srcB);
            unsigned w03 = (unsigned)__shfl((int)pk2v[2 * kb][1], srcB);
            unsigned w13 = (unsigned)__shfl((int)pk2v[2 * kb + 1][1], srcB);
            union { unsigned u[4]; f16x8 v; } pa2;
            pa2.u[0] = hiSel ? w10 : w00;
            pa2.u[1] = hiSel ? w11 : w01;
            pa2.u[2] = hiSel ? w12 : w02;
            pa2.u[3] = hiSel ? w13 : w03;
            __builtin_amdgcn_s_setprio(1);
            #pragma unroll
            for (int nt = 0; nt < 8; ++nt) {
                O1[nt] = __builtin_amdgcn_mfma_f32_16x16x32_f16(pa1.v, vf[nt], O1[nt], 0, 0, 0);
                O2[nt] = __builtin_amdgcn_mfma_f32_16x16x32_f16(pa2.v, vf[nt], O2[nt], 0, 0, 0);
            }
            __builtin_amdgcn_s_setprio(0);
        }
        __syncthreads();   // drains vmcnt (next tile landed) + gates buffer reuse
    }

    // ---- epilogue: combine paths, write fp16 (aliases this block's Q slice)
    float il1[4], il2[4];
    #pragma unroll
    for (int r = 0; r < 4; ++r) {
        float L1 = __shfl(l1, (g << 2) | r);
        float L2 = __shfl(l2, (g << 2) | r);
        il1[r] = 1.f / L1;
        il2[r] = lam / L2;
    }
    const size_t obase = (size_t)(b * T_ + q0) * D_ + h * DH;
    #pragma unroll
    for (int nt = 0; nt < 8; ++nt)
        #pragma unroll
        for (int r = 0; r < 4; ++r) {
            float o = O1[nt][r] * il1[r] - O2[nt][r] * il2[r];
            Qh[obase + (size_t)(g * 4 + r) * D_ + nt * 16 + c] = (_Float16)o;
        }
}

// ---------------------------------------------------------------------------
extern "C" void kernel_launch(void* const* d_in, const int* in_sizes, int n_in,
                              void* d_out, int out_size, void* d_ws, size_t ws_size,
                              hipStream_t stream) {
    const float* x    = (const float*)d_in[0];
    const float* W_q  = (const float*)d_in[1];
    const float* W_k  = (const float*)d_in[2];
    const float* W_v  = (const float*)d_in[3];
    const float* W_o  = (const float*)d_in[4];
    const float* lamp = (const float*)d_in[5];
    float* out = (float*)d_out;

    const size_t PL = (size_t)BT * D_;               // 8.4M elems
    const size_t WL = (size_t)D_ * D_;               // 4.2M elems
    _Float16* Xh = (_Float16*)d_ws;                  // 16 MB
    _Float16* Wq = Xh + PL;                          // 8 MB (recycled for W_o)
    _Float16* Wk = Wq + WL;                          // 8 MB
    _Float16* Wv = Wk + WL;                          // 8 MB
    _Float16* Qh = Wv + WL;                          // 16 MB (attn out alias)
    _Float16* Kh = Qh + PL;                          // 16 MB
    _Float16* Vt = Kh + PL;                          // 16 MB  (total 92.3 MB)
    _Float16* Wo = Wq;                               // dead after Q-GEMM

    // one fused convert launch: x, W_q, W_k, W_v
    dim3 gc((unsigned)(PL / 8 + 255) / 256, 4);
    f32_to_f16_multi<<<gc, 256, 0, stream>>>(x,   Xh, (int)(PL / 8),
                                             W_q, Wq, (int)(WL / 8),
                                             W_k, Wk, (int)(WL / 8),
                                             W_v, Wv, (int)(WL / 8));

    dim3 gg(512);  // (M/128)*(N/128) = 32*16
    gemm16<1><<<gg, 256, 0, stream>>>(Xh, Wq, nullptr, Qh, nullptr, BT, D_, D_);
    gemm16<1><<<gg, 256, 0, stream>>>(Xh, Wk, nullptr, Kh, nullptr, BT, D_, D_);
    gemm16<2><<<gg, 256, 0, stream>>>(Xh, Wv, nullptr, nullptr, Vt, BT, D_, D_);

    f32_to_f16<<<(int)(WL / 8 / 256), 256, 0, stream>>>(W_o, Wo, (int)(WL / 8));

    dim3 ga(T_ / 128, H_, B_);                       // (16, 16, 2)
    diff_attn_f16<<<ga, 512, 0, stream>>>(Qh, Kh, Vt, lamp);

    gemm16<0><<<gg, 256, 0, stream>>>(Qh, Wo, out, nullptr, nullptr, BT, D_, D_);
}

// Round 7
// 387.905 us; speedup vs baseline: 1.3219x; 1.3219x over previous
//
#include <hip/hip_runtime.h>
#include <math.h>

#define B_  2
#define T_  2048
#define D_  2048
#define H_  16
#define DH  128
#define BT  (B_ * T_)          // 4096 rows

typedef float    f32x4 __attribute__((ext_vector_type(4)));
typedef _Float16 f16x8 __attribute__((ext_vector_type(8)));
typedef __fp16   fp16x2 __attribute__((ext_vector_type(2)));

typedef __attribute__((address_space(1))) const void* gas_t;
typedef __attribute__((address_space(3))) void*       las_t;

__device__ __forceinline__ void gll16(const void* g, void* l) {
    __builtin_amdgcn_global_load_lds((gas_t)g, (las_t)l, 16, 0, 0);
}

__device__ __forceinline__ unsigned short h16bits(float f) {
    union { _Float16 h; unsigned short u; } c; c.h = (_Float16)f; return c.u;
}
// pack 2 fp32 -> 2 fp16 (RTZ) in one v_cvt_pkrtz_f16_f32
__device__ __forceinline__ unsigned pk2h(float a, float b) {
    union { fp16x2 h; unsigned u; } c;
    c.h = __builtin_amdgcn_cvt_pkrtz(a, b);
    return c.u;
}

// ---------------------------------------------------------------------------
// fp32 -> fp16 conversion, 4 segments in one launch (blockIdx.y = segment)
// ---------------------------------------------------------------------------
__global__ __launch_bounds__(256)
void f32_to_f16_multi(const float* __restrict__ s0, _Float16* __restrict__ d0, int n0,
                      const float* __restrict__ s1, _Float16* __restrict__ d1, int n1,
                      const float* __restrict__ s2, _Float16* __restrict__ d2, int n2,
                      const float* __restrict__ s3, _Float16* __restrict__ d3, int n3) {
    const float* s; _Float16* d; int n;
    switch (blockIdx.y) {
        case 0:  s = s0; d = d0; n = n0; break;
        case 1:  s = s1; d = d1; n = n1; break;
        case 2:  s = s2; d = d2; n = n2; break;
        default: s = s3; d = d3; n = n3; break;
    }
    int i = blockIdx.x * 256 + threadIdx.x;
    if (i >= n) return;
    const float4 a = *(const float4*)(s + (size_t)i * 8);
    const float4 b = *(const float4*)(s + (size_t)i * 8 + 4);
    f16x8 o;
    o[0] = (_Float16)a.x; o[1] = (_Float16)a.y; o[2] = (_Float16)a.z; o[3] = (_Float16)a.w;
    o[4] = (_Float16)b.x; o[5] = (_Float16)b.y; o[6] = (_Float16)b.z; o[7] = (_Float16)b.w;
    *(f16x8*)(d + (size_t)i * 8) = o;
}

__global__ __launch_bounds__(256)
void f32_to_f16(const float* __restrict__ in, _Float16* __restrict__ out, int n8) {
    int i = blockIdx.x * 256 + threadIdx.x;
    if (i >= n8) return;
    const float4 a = *(const float4*)(in + (size_t)i * 8);
    const float4 b = *(const float4*)(in + (size_t)i * 8 + 4);
    f16x8 o;
    o[0] = (_Float16)a.x; o[1] = (_Float16)a.y; o[2] = (_Float16)a.z; o[3] = (_Float16)a.w;
    o[4] = (_Float16)b.x; o[5] = (_Float16)b.y; o[6] = (_Float16)b.z; o[7] = (_Float16)b.w;
    *(f16x8*)(out + (size_t)i * 8) = o;
}

// ---------------------------------------------------------------------------
// fp16 MFMA GEMM (m97 structure): C = A @ W^T. A,W fp16 planes.
// 128x128 tile, BK=64, 4 waves, global_load_lds(16B) staging, XOR-swizzled
// LDS via pre-permuted global source granules + linear LDS dest.
// EPI: 0 = fp32 C, 1 = fp16 C, 2 = transposed fp16 Vt[(b*D+n)*T + t].
// ---------------------------------------------------------------------------
#define BKK 64

template<int EPI>
__global__ __launch_bounds__(256, 3)
void gemm16(const _Float16* __restrict__ Ag, const _Float16* __restrict__ Bg,
            float* __restrict__ Cf, _Float16* __restrict__ C16,
            _Float16* __restrict__ Vt, int M, int N, int K) {
    __shared__ _Float16 As[128 * BKK];
    __shared__ _Float16 Bs[128 * BKK];

    const int tid  = threadIdx.x;
    const int lane = tid & 63;
    const int w    = tid >> 6;
    const int wr   = w >> 1, wc = w & 1;
    const int c    = lane & 15, g = lane >> 4;

    const int nwg = gridDim.x;
    const int bid = blockIdx.x;
    const int swz = (bid & 7) * (nwg >> 3) + (bid >> 3);
    const int nb  = N / 128;
    const int bm  = (swz / nb) * 128;
    const int bn  = (swz % nb) * 128;

    const int srow = tid >> 3;                       // 0..31 (+ i*32)
    const int sg   = (tid & 7) ^ (srow & 7);         // pre-permuted source granule
    const _Float16* Ab = Ag + (size_t)(bm + srow) * K + sg * 8;
    const _Float16* Bb = Bg + (size_t)(bn + srow) * K + sg * 8;

    f32x4 acc[4][4];
    #pragma unroll
    for (int mi = 0; mi < 4; ++mi)
        #pragma unroll
        for (int ni = 0; ni < 4; ++ni)
            #pragma unroll
            for (int r = 0; r < 4; ++r) acc[mi][ni][r] = 0.f;

    for (int k0 = 0; k0 < K; k0 += BKK) {
        __syncthreads();
        #pragma unroll
        for (int i = 0; i < 4; ++i) {
            gll16(Ab + (size_t)i * 32 * K + k0, &As[(i * 256 + tid) * 8]);
            gll16(Bb + (size_t)i * 32 * K + k0, &Bs[(i * 256 + tid) * 8]);
        }
        __syncthreads();

        #pragma unroll
        for (int kc = 0; kc < 2; ++kc) {
            f16x8 fa[4], fb[4];
            #pragma unroll
            for (int mi = 0; mi < 4; ++mi) {
                const int row = wr * 64 + mi * 16 + c;
                fa[mi] = *(const f16x8*)&As[row * 64 + (((kc * 4 + g) ^ (c & 7)) * 8)];
            }
            #pragma unroll
            for (int ni = 0; ni < 4; ++ni) {
                const int row = wc * 64 + ni * 16 + c;
                fb[ni] = *(const f16x8*)&Bs[row * 64 + (((kc * 4 + g) ^ (c & 7)) * 8)];
            }
            #pragma unroll
            for (int mi = 0; mi < 4; ++mi)
                #pragma unroll
                for (int ni = 0; ni < 4; ++ni)
                    acc[mi][ni] = __builtin_amdgcn_mfma_f32_16x16x32_f16(fa[mi], fb[ni], acc[mi][ni], 0, 0, 0);
        }
    }

    #pragma unroll
    for (int mi = 0; mi < 4; ++mi) {
        #pragma unroll
        for (int ni = 0; ni < 4; ++ni) {
            const int m0 = bm + wr * 64 + mi * 16 + g * 4;
            const int n  = bn + wc * 64 + ni * 16 + c;
            if constexpr (EPI == 0) {
                #pragma unroll
                for (int r = 0; r < 4; ++r)
                    Cf[(size_t)(m0 + r) * N + n] = acc[mi][ni][r];
            } else if constexpr (EPI == 1) {
                #pragma unroll
                for (int r = 0; r < 4; ++r)
                    C16[(size_t)(m0 + r) * N + n] = (_Float16)acc[mi][ni][r];
            } else {
                const int bb = m0 >> 11, t = m0 & (T_ - 1);
                ushort4 o;
                o.x = h16bits(acc[mi][ni][0]); o.y = h16bits(acc[mi][ni][1]);
                o.z = h16bits(acc[mi][ni][2]); o.w = h16bits(acc[mi][ni][3]);
                *(ushort4*)&Vt[((size_t)bb * D_ + n) * T_ + t] = o;
            }
        }
    }
}

// ---------------------------------------------------------------------------
// Flash differential attention, PATH-SPLIT: 256 threads = 4 waves =
// 2 q-subtiles x 2 paths. Each wave computes ONE path (64 Q/K dims) for
// its 16 q-rows: half the accumulator state (O[8] not O1+O2), half the
// softmax chain. LDS 32 KB single-buffered (K 16K + V 16K) -> 4 blocks/CU
// with VGPR<=128 (launch_bounds(256,4)) = 16 waves/CU. Paths combined in
// epilogue via LDS (path1 writes lam/l2-scaled O2; path0 subtracts).
// ---------------------------------------------------------------------------
#define QB  32
#define KVB 64

__device__ __forceinline__ void softmax_upd(f32x4 s[4], f32x4 O[8],
                                            float& m, float& l,
                                            unsigned pk[4][2], int g) {
    const float C1 = 0.125f * 1.44269504089f;   // log2(e)/sqrt(64)
    float tmax = -1e30f;
    #pragma unroll
    for (int mt = 0; mt < 4; ++mt)
        #pragma unroll
        for (int r = 0; r < 4; ++r) {
            s[mt][r] *= C1;                      // exp2 domain
            tmax = fmaxf(tmax, s[mt][r]);
        }
    tmax = fmaxf(tmax, __shfl_xor(tmax, 16));
    tmax = fmaxf(tmax, __shfl_xor(tmax, 32));
    if (!__all(tmax <= m + 8.f)) {               // defer-max rescale (rare)
        float mnew = fmaxf(m, tmax);
        float al   = exp2f(m - mnew);
        #pragma unroll
        for (int r = 0; r < 4; ++r) {
            float alr = __shfl(al, (g << 2) | r);
            #pragma unroll
            for (int nt = 0; nt < 8; ++nt) O[nt][r] *= alr;
        }
        l *= al;
        m  = mnew;
    }
    float tsum = 0.f;
    #pragma unroll
    for (int mt = 0; mt < 4; ++mt)
        #pragma unroll
        for (int r = 0; r < 4; ++r) {
            float p = exp2f(s[mt][r] - m);       // bounded by 2^8
            s[mt][r] = p; tsum += p;
        }
    tsum += __shfl_xor(tsum, 16);
    tsum += __shfl_xor(tsum, 32);
    l += tsum;
    #pragma unroll
    for (int mt = 0; mt < 4; ++mt) {
        pk[mt][0] = pk2h(s[mt][0], s[mt][1]);
        pk[mt][1] = pk2h(s[mt][2], s[mt][3]);
    }
}

__global__ __launch_bounds__(256, 4)
void diff_attn_f16(_Float16* Qh,
                   const _Float16* __restrict__ Kh,
                   const _Float16* __restrict__ Vt,
                   const float* __restrict__ lambda_param) {
    __shared__ __align__(16) char smem[32 * 1024];
    _Float16* k_s = (_Float16*)smem;               // [64*128]  16 KB
    _Float16* v_s = (_Float16*)(smem + 16384);     // [128*64]  16 KB
    float*    ob  = (float*)smem;                  // epilogue: [2][16][132] 16.9 KB

    const int tid  = threadIdx.x;
    const int lane = tid & 63;
    const int w    = tid >> 6;                     // 0..3
    const int qsub = w >> 1;                       // 0..1
    const int path = w & 1;                        // 0..1
    const int b    = blockIdx.z, h = blockIdx.y;
    const int t0   = blockIdx.x * QB;
    const int c    = lane & 15;
    const int g    = lane >> 4;

    const float lam = 1.f / (1.f + __expf(-lambda_param[h]));

    // ---- Q fragments for THIS path only (dims path*64 .. path*64+63)
    const int q0 = t0 + qsub * 16;
    const _Float16* Qg = Qh + (size_t)(b * T_ + q0 + c) * D_ + h * DH + path * 64;
    f16x8 qf[2];
    qf[0] = *(const f16x8*)&Qg[g * 8];
    qf[1] = *(const f16x8*)&Qg[32 + g * 8];

    f32x4 O[8];
    #pragma unroll
    for (int nt = 0; nt < 8; ++nt)
        #pragma unroll
        for (int r = 0; r < 4; ++r) O[nt][r] = 0.f;
    float m = -1e30f, l = 0.f;

    // staging geometry (256 threads, lane-linear LDS dests for gll)
    const int kkey = tid >> 4;                     // 0..15 (+ i*16; 16%8==0 so row&7 = kkey&7)
    const int kgs  = (tid & 15) ^ (kkey & 7);
    const int vd   = tid >> 3;                     // 0..31 (+ i*32; row&7 = vd&7)
    const int vgs  = (tid & 7) ^ (vd & 7);
    const size_t rowK = (size_t)(b * T_);
    const size_t rowV = (size_t)(b * D_ + h * DH);

    const int NT = T_ / KVB;
    for (int t = 0; t < NT; ++t) {
        const int s0 = t * KVB;
        __syncthreads();                           // prev tile consumed
        #pragma unroll
        for (int i = 0; i < 4; ++i) {
            const size_t goff = (rowK + s0 + i * 16 + kkey) * (size_t)D_ + h * DH + kgs * 8;
            gll16(&Kh[goff], &k_s[(i * 256 + tid) * 8]);
        }
        #pragma unroll
        for (int i = 0; i < 4; ++i) {
            const size_t goff = (rowV + i * 32 + vd) * (size_t)T_ + s0 + vgs * 8;
            gll16(&Vt[goff], &v_s[(i * 256 + tid) * 8]);
        }
        __syncthreads();                           // drains vmcnt: tile ready

        // ---- QK^T for this path: A = K (LDS, dims path*64..+63), B = Q (regs)
        f32x4 s[4];
        #pragma unroll
        for (int mt = 0; mt < 4; ++mt)
            #pragma unroll
            for (int r = 0; r < 4; ++r) s[mt][r] = 0.f;
        __builtin_amdgcn_s_setprio(1);
        #pragma unroll
        for (int mt = 0; mt < 4; ++mt) {
            const int key  = mt * 16 + c;
            const int krow = key * 128;
            #pragma unroll
            for (int kb = 0; kb < 2; ++kb) {
                const int gp = (((path * 8 + kb * 4 + g)) ^ (key & 7)) * 8;
                f16x8 kf = *(const f16x8*)&k_s[krow + gp];
                s[mt] = __builtin_amdgcn_mfma_f32_16x16x32_f16(kf, qf[kb], s[mt], 0, 0, 0);
            }
        }
        __builtin_amdgcn_s_setprio(0);

        unsigned pk[4][2];
        softmax_upd(s, O, m, l, pk, g);

        // ---- PV: A = P (shuffled to A-layout), B = V fragments
        const int srcA = ((2 * (g & 1)) << 4) | c;
        const int srcB = ((2 * (g & 1) + 1) << 4) | c;
        const bool hiSel = (g & 2) != 0;
        #pragma unroll
        for (int kb = 0; kb < 2; ++kb) {
            f16x8 vf[8];
            #pragma unroll
            for (int nt = 0; nt < 8; ++nt) {
                const int d  = nt * 16 + c;
                const int gp = ((4 * kb + g) ^ (d & 7)) * 8;
                vf[nt] = *(const f16x8*)&v_s[d * 64 + gp];
            }
            unsigned u00 = (unsigned)__shfl((int)pk[2 * kb][0], srcA);
            unsigned u10 = (unsigned)__shfl((int)pk[2 * kb + 1][0], srcA);
            unsigned u01 = (unsigned)__shfl((int)pk[2 * kb][1], srcA);
            unsigned u11 = (unsigned)__shfl((int)pk[2 * kb + 1][1], srcA);
            unsigned u02 = (unsigned)__shfl((int)pk[2 * kb][0], srcB);
            unsigned u12 = (unsigned)__shfl((int)pk[2 * kb + 1][0], srcB);
            unsigned u03 = (unsigned)__shfl((int)pk[2 * kb][1], srcB);
            unsigned u13 = (unsigned)__shfl((int)pk[2 * kb + 1][1], srcB);
            union { unsigned u[4]; f16x8 v; } pa;
            pa.u[0] = hiSel ? u10 : u00;
            pa.u[1] = hiSel ? u11 : u01;
            pa.u[2] = hiSel ? u12 : u02;
            pa.u[3] = hiSel ? u13 : u03;
            __builtin_amdgcn_s_setprio(1);
            #pragma unroll
            for (int nt = 0; nt < 8; ++nt)
                O[nt] = __builtin_amdgcn_mfma_f32_16x16x32_f16(pa.v, vf[nt], O[nt], 0, 0, 0);
            __builtin_amdgcn_s_setprio(0);
        }
    }

    // ---- epilogue: combine the two paths via LDS
    float il[4];
    #pragma unroll
    for (int r = 0; r < 4; ++r) {
        float L = __shfl(l, (g << 2) | r);
        il[r] = (path ? lam : 1.f) / L;
    }

    __syncthreads();                               // all K/V reads done (ob aliases)
    if (path) {
        float* obp = ob + qsub * 16 * 132;
        #pragma unroll
        for (int nt = 0; nt < 8; ++nt)
            #pragma unroll
            for (int r = 0; r < 4; ++r)
                obp[(g * 4 + r) * 132 + nt * 16 + c] = O[nt][r] * il[r];
    }
    __syncthreads();
    if (!path) {
        const float* obp = ob + qsub * 16 * 132;
        const size_t obase = (size_t)(b * T_ + q0) * D_ + h * DH;
        #pragma unroll
        for (int nt = 0; nt < 8; ++nt)
            #pragma unroll
            for (int r = 0; r < 4; ++r) {
                float o = O[nt][r] * il[r] - obp[(g * 4 + r) * 132 + nt * 16 + c];
                Qh[obase + (size_t)(g * 4 + r) * D_ + nt * 16 + c] = (_Float16)o;
            }
    }
}

// ---------------------------------------------------------------------------
extern "C" void kernel_launch(void* const* d_in, const int* in_sizes, int n_in,
                              void* d_out, int out_size, void* d_ws, size_t ws_size,
                              hipStream_t stream) {
    const float* x    = (const float*)d_in[0];
    const float* W_q  = (const float*)d_in[1];
    const float* W_k  = (const float*)d_in[2];
    const float* W_v  = (const float*)d_in[3];
    const float* W_o  = (const float*)d_in[4];
    const float* lamp = (const float*)d_in[5];
    float* out = (float*)d_out;

    const size_t PL = (size_t)BT * D_;               // 8.4M elems
    const size_t WL = (size_t)D_ * D_;               // 4.2M elems
    _Float16* Xh = (_Float16*)d_ws;                  // 16 MB
    _Float16* Wq = Xh + PL;                          // 8 MB (recycled for W_o)
    _Float16* Wk = Wq + WL;                          // 8 MB
    _Float16* Wv = Wk + WL;                          // 8 MB
    _Float16* Qh = Wv + WL;                          // 16 MB (attn out alias)
    _Float16* Kh = Qh + PL;                          // 16 MB
    _Float16* Vt = Kh + PL;                          // 16 MB  (total 92.3 MB)
    _Float16* Wo = Wq;                               // dead after Q-GEMM

    // one fused convert launch: x, W_q, W_k, W_v
    dim3 gc((unsigned)(PL / 8 + 255) / 256, 4);
    f32_to_f16_multi<<<gc, 256, 0, stream>>>(x,   Xh, (int)(PL / 8),
                                             W_q, Wq, (int)(WL / 8),
                                             W_k, Wk, (int)(WL / 8),
                                             W_v, Wv, (int)(WL / 8));

    dim3 gg(512);  // (M/128)*(N/128) = 32*16
    gemm16<1><<<gg, 256, 0, stream>>>(Xh, Wq, nullptr, Qh, nullptr, BT, D_, D_);
    gemm16<1><<<gg, 256, 0, stream>>>(Xh, Wk, nullptr, Kh, nullptr, BT, D_, D_);
    gemm16<2><<<gg, 256, 0, stream>>>(Xh, Wv, nullptr, nullptr, Vt, BT, D_, D_);

    f32_to_f16<<<(int)(WL / 8 / 256), 256, 0, stream>>>(W_o, Wo, (int)(WL / 8));

    dim3 ga(T_ / QB, H_, B_);                        // (64, 16, 2)
    diff_attn_f16<<<ga, 256, 0, stream>>>(Qh, Kh, Vt, lamp);

    gemm16<0><<<gg, 256, 0, stream>>>(Qh, Wo, out, nullptr, nullptr, BT, D_, D_);
}

// Round 8
// 367.267 us; speedup vs baseline: 1.3962x; 1.0562x over previous
//
#include <hip/hip_runtime.h>
#include <math.h>

#define B_  2
#define T_  2048
#define D_  2048
#define H_  16
#define DH  128
#define BT  (B_ * T_)          // 4096 rows

typedef float    f32x4 __attribute__((ext_vector_type(4)));
typedef _Float16 f16x8 __attribute__((ext_vector_type(8)));
typedef __fp16   fp16x2 __attribute__((ext_vector_type(2)));

typedef __attribute__((address_space(1))) const void* gas_t;
typedef __attribute__((address_space(3))) void*       las_t;

__device__ __forceinline__ void gll16(const void* g, void* l) {
    __builtin_amdgcn_global_load_lds((gas_t)g, (las_t)l, 16, 0, 0);
}

__device__ __forceinline__ unsigned short h16bits(float f) {
    union { _Float16 h; unsigned short u; } c; c.h = (_Float16)f; return c.u;
}
// pack 2 fp32 -> 2 fp16 (RTZ) in one v_cvt_pkrtz_f16_f32
__device__ __forceinline__ unsigned pk2h(float a, float b) {
    union { fp16x2 h; unsigned u; } c;
    c.h = __builtin_amdgcn_cvt_pkrtz(a, b);
    return c.u;
}

// ---------------------------------------------------------------------------
// fp32 -> fp16 conversion, 4 segments in one launch (blockIdx.y = segment)
// ---------------------------------------------------------------------------
__global__ __launch_bounds__(256)
void f32_to_f16_multi(const float* __restrict__ s0, _Float16* __restrict__ d0, int n0,
                      const float* __restrict__ s1, _Float16* __restrict__ d1, int n1,
                      const float* __restrict__ s2, _Float16* __restrict__ d2, int n2,
                      const float* __restrict__ s3, _Float16* __restrict__ d3, int n3) {
    const float* s; _Float16* d; int n;
    switch (blockIdx.y) {
        case 0:  s = s0; d = d0; n = n0; break;
        case 1:  s = s1; d = d1; n = n1; break;
        case 2:  s = s2; d = d2; n = n2; break;
        default: s = s3; d = d3; n = n3; break;
    }
    int i = blockIdx.x * 256 + threadIdx.x;
    if (i >= n) return;
    const float4 a = *(const float4*)(s + (size_t)i * 8);
    const float4 b = *(const float4*)(s + (size_t)i * 8 + 4);
    f16x8 o;
    o[0] = (_Float16)a.x; o[1] = (_Float16)a.y; o[2] = (_Float16)a.z; o[3] = (_Float16)a.w;
    o[4] = (_Float16)b.x; o[5] = (_Float16)b.y; o[6] = (_Float16)b.z; o[7] = (_Float16)b.w;
    *(f16x8*)(d + (size_t)i * 8) = o;
}

__global__ __launch_bounds__(256)
void f32_to_f16(const float* __restrict__ in, _Float16* __restrict__ out, int n8) {
    int i = blockIdx.x * 256 + threadIdx.x;
    if (i >= n8) return;
    const float4 a = *(const float4*)(in + (size_t)i * 8);
    const float4 b = *(const float4*)(in + (size_t)i * 8 + 4);
    f16x8 o;
    o[0] = (_Float16)a.x; o[1] = (_Float16)a.y; o[2] = (_Float16)a.z; o[3] = (_Float16)a.w;
    o[4] = (_Float16)b.x; o[5] = (_Float16)b.y; o[6] = (_Float16)b.z; o[7] = (_Float16)b.w;
    *(f16x8*)(out + (size_t)i * 8) = o;
}

// ---------------------------------------------------------------------------
// fp16 MFMA GEMM (m97 structure): C = A @ W^T. A,W fp16 planes.
// 128x128 tile, BK=64, 4 waves, global_load_lds(16B) staging, XOR-swizzled
// LDS via pre-permuted global source granules + linear LDS dest.
// EPI: 0 = fp32 C, 1 = fp16 C, 2 = transposed fp16 Vt[(b*D+n)*T + t].
// ---------------------------------------------------------------------------
#define BKK 64

template<int EPI>
__global__ __launch_bounds__(256, 3)
void gemm16(const _Float16* __restrict__ Ag, const _Float16* __restrict__ Bg,
            float* __restrict__ Cf, _Float16* __restrict__ C16,
            _Float16* __restrict__ Vt, int M, int N, int K) {
    __shared__ _Float16 As[128 * BKK];
    __shared__ _Float16 Bs[128 * BKK];

    const int tid  = threadIdx.x;
    const int lane = tid & 63;
    const int w    = tid >> 6;
    const int wr   = w >> 1, wc = w & 1;
    const int c    = lane & 15, g = lane >> 4;

    const int nwg = gridDim.x;
    const int bid = blockIdx.x;
    const int swz = (bid & 7) * (nwg >> 3) + (bid >> 3);
    const int nb  = N / 128;
    const int bm  = (swz / nb) * 128;
    const int bn  = (swz % nb) * 128;

    const int srow = tid >> 3;                       // 0..31 (+ i*32)
    const int sg   = (tid & 7) ^ (srow & 7);         // pre-permuted source granule
    const _Float16* Ab = Ag + (size_t)(bm + srow) * K + sg * 8;
    const _Float16* Bb = Bg + (size_t)(bn + srow) * K + sg * 8;

    f32x4 acc[4][4];
    #pragma unroll
    for (int mi = 0; mi < 4; ++mi)
        #pragma unroll
        for (int ni = 0; ni < 4; ++ni)
            #pragma unroll
            for (int r = 0; r < 4; ++r) acc[mi][ni][r] = 0.f;

    for (int k0 = 0; k0 < K; k0 += BKK) {
        __syncthreads();
        #pragma unroll
        for (int i = 0; i < 4; ++i) {
            gll16(Ab + (size_t)i * 32 * K + k0, &As[(i * 256 + tid) * 8]);
            gll16(Bb + (size_t)i * 32 * K + k0, &Bs[(i * 256 + tid) * 8]);
        }
        __syncthreads();

        #pragma unroll
        for (int kc = 0; kc < 2; ++kc) {
            f16x8 fa[4], fb[4];
            #pragma unroll
            for (int mi = 0; mi < 4; ++mi) {
                const int row = wr * 64 + mi * 16 + c;
                fa[mi] = *(const f16x8*)&As[row * 64 + (((kc * 4 + g) ^ (c & 7)) * 8)];
            }
            #pragma unroll
            for (int ni = 0; ni < 4; ++ni) {
                const int row = wc * 64 + ni * 16 + c;
                fb[ni] = *(const f16x8*)&Bs[row * 64 + (((kc * 4 + g) ^ (c & 7)) * 8)];
            }
            #pragma unroll
            for (int mi = 0; mi < 4; ++mi)
                #pragma unroll
                for (int ni = 0; ni < 4; ++ni)
                    acc[mi][ni] = __builtin_amdgcn_mfma_f32_16x16x32_f16(fa[mi], fb[ni], acc[mi][ni], 0, 0, 0);
        }
    }

    #pragma unroll
    for (int mi = 0; mi < 4; ++mi) {
        #pragma unroll
        for (int ni = 0; ni < 4; ++ni) {
            const int m0 = bm + wr * 64 + mi * 16 + g * 4;
            const int n  = bn + wc * 64 + ni * 16 + c;
            if constexpr (EPI == 0) {
                #pragma unroll
                for (int r = 0; r < 4; ++r)
                    Cf[(size_t)(m0 + r) * N + n] = acc[mi][ni][r];
            } else if constexpr (EPI == 1) {
                #pragma unroll
                for (int r = 0; r < 4; ++r)
                    C16[(size_t)(m0 + r) * N + n] = (_Float16)acc[mi][ni][r];
            } else {
                const int bb = m0 >> 11, t = m0 & (T_ - 1);
                ushort4 o;
                o.x = h16bits(acc[mi][ni][0]); o.y = h16bits(acc[mi][ni][1]);
                o.z = h16bits(acc[mi][ni][2]); o.w = h16bits(acc[mi][ni][3]);
                *(ushort4*)&Vt[((size_t)bb * D_ + n) * T_ + t] = o;
            }
        }
    }
}

// ---------------------------------------------------------------------------
// Flash differential attention. Block = 256 threads = 4 waves =
// 2 q-subtiles(32 rows) x 2 paths; wave owns 32 q-rows, ONE path.
// K-frag reads feed 2 MFMAs (both q-halves), staging addr = pointer += const.
// LDS 32 KB K+V single-buffered (+ epilogue reuse 33.8 KB); 4 blocks/CU.
// Paths combined in epilogue via LDS.
// ---------------------------------------------------------------------------
#define QB  64
#define KVB 64

__device__ __forceinline__ void softmax_upd(f32x4 s[4], f32x4 O[8],
                                            float& m, float& l,
                                            unsigned pk[4][2], int g) {
    const float C1 = 0.125f * 1.44269504089f;   // log2(e)/sqrt(64)
    float tmax = -1e30f;
    #pragma unroll
    for (int mt = 0; mt < 4; ++mt)
        #pragma unroll
        for (int r = 0; r < 4; ++r) {
            s[mt][r] *= C1;                      // exp2 domain
            tmax = fmaxf(tmax, s[mt][r]);
        }
    tmax = fmaxf(tmax, __shfl_xor(tmax, 16));
    tmax = fmaxf(tmax, __shfl_xor(tmax, 32));
    if (!__all(tmax <= m + 8.f)) {               // defer-max rescale (rare)
        float mnew = fmaxf(m, tmax);
        float al   = exp2f(m - mnew);
        #pragma unroll
        for (int r = 0; r < 4; ++r) {
            float alr = __shfl(al, (g << 2) | r);
            #pragma unroll
            for (int nt = 0; nt < 8; ++nt) O[nt][r] *= alr;
        }
        l *= al;
        m  = mnew;
    }
    float tsum = 0.f;
    #pragma unroll
    for (int mt = 0; mt < 4; ++mt)
        #pragma unroll
        for (int r = 0; r < 4; ++r) {
            float p = exp2f(s[mt][r] - m);       // bounded by 2^8
            s[mt][r] = p; tsum += p;
        }
    tsum += __shfl_xor(tsum, 16);
    tsum += __shfl_xor(tsum, 32);
    l += tsum;
    #pragma unroll
    for (int mt = 0; mt < 4; ++mt) {
        pk[mt][0] = pk2h(s[mt][0], s[mt][1]);
        pk[mt][1] = pk2h(s[mt][2], s[mt][3]);
    }
}

__global__ __launch_bounds__(256, 3)
void diff_attn_f16(_Float16* Qh,
                   const _Float16* __restrict__ Kh,
                   const _Float16* __restrict__ Vt,
                   const float* __restrict__ lambda_param) {
    __shared__ __align__(16) char smem[QB * 132 * 4];   // 33792 B
    _Float16* k_s = (_Float16*)smem;               // [64*128]  16 KB
    _Float16* v_s = (_Float16*)(smem + 16384);     // [128*64]  16 KB
    float*    ob  = (float*)smem;                  // epilogue: [64][132]

    const int tid  = threadIdx.x;
    const int lane = tid & 63;
    const int w    = tid >> 6;                     // 0..3
    const int qsub = w >> 1;                       // 0..1  (32-row half)
    const int path = w & 1;                        // 0..1
    const int b    = blockIdx.z, h = blockIdx.y;
    const int t0   = blockIdx.x * QB;
    const int c    = lane & 15;
    const int g    = lane >> 4;

    const float lam = 1.f / (1.f + __expf(-lambda_param[h]));

    // ---- Q fragments for THIS path, two 16-row subtiles (dims path*64..+63)
    const int q0 = t0 + qsub * 32;
    const _Float16* Qg = Qh + (size_t)(b * T_ + q0 + c) * D_ + h * DH + path * 64;
    f16x8 qf[2][2];
    #pragma unroll
    for (int qh = 0; qh < 2; ++qh) {
        qf[qh][0] = *(const f16x8*)&Qg[(size_t)qh * 16 * D_ + g * 8];
        qf[qh][1] = *(const f16x8*)&Qg[(size_t)qh * 16 * D_ + 32 + g * 8];
    }

    f32x4 O[2][8];
    #pragma unroll
    for (int qh = 0; qh < 2; ++qh)
        #pragma unroll
        for (int nt = 0; nt < 8; ++nt)
            #pragma unroll
            for (int r = 0; r < 4; ++r) O[qh][nt][r] = 0.f;
    float m[2] = {-1e30f, -1e30f}, l[2] = {0.f, 0.f};

    // staging geometry: pointer-increment (no per-tile address mul)
    const int kkey = tid >> 4;                     // 0..15 (+ i*16)
    const int kgs  = (tid & 15) ^ (kkey & 7);
    const int vd   = tid >> 3;                     // 0..31 (+ i*32)
    const int vgs  = (tid & 7) ^ (vd & 7);
    const char* kp[4];
    const char* vp[4];
    #pragma unroll
    for (int i = 0; i < 4; ++i) {
        kp[i] = (const char*)(Kh + ((size_t)(b * T_ + i * 16 + kkey)) * D_ + h * DH + kgs * 8);
        vp[i] = (const char*)(Vt + ((size_t)(b * D_ + h * DH + i * 32 + vd)) * T_ + vgs * 8);
    }
    const size_t KADV = (size_t)KVB * D_ * sizeof(_Float16);   // 256 KB
    const size_t VADV = (size_t)KVB * sizeof(_Float16);        // 128 B

    const int NT = T_ / KVB;
    for (int t = 0; t < NT; ++t) {
        __syncthreads();                           // prev tile consumed
        #pragma unroll
        for (int i = 0; i < 4; ++i) {
            gll16(kp[i], &k_s[(i * 256 + tid) * 8]);
            gll16(vp[i], &v_s[(i * 256 + tid) * 8]);
            kp[i] += KADV; vp[i] += VADV;
        }
        __syncthreads();                           // drains vmcnt: tile ready

        // ---- QK^T, both q-halves share each K fragment read
        f32x4 s[2][4];
        #pragma unroll
        for (int qh = 0; qh < 2; ++qh)
            #pragma unroll
            for (int mt = 0; mt < 4; ++mt)
                #pragma unroll
                for (int r = 0; r < 4; ++r) s[qh][mt][r] = 0.f;
        __builtin_amdgcn_s_setprio(1);
        #pragma unroll
        for (int mt = 0; mt < 4; ++mt) {
            const int key  = mt * 16 + c;
            const int krow = key * 128;
            #pragma unroll
            for (int kb = 0; kb < 2; ++kb) {
                const int gp = ((path * 8 + kb * 4 + g) ^ (key & 7)) * 8;
                f16x8 kf = *(const f16x8*)&k_s[krow + gp];
                s[0][mt] = __builtin_amdgcn_mfma_f32_16x16x32_f16(kf, qf[0][kb], s[0][mt], 0, 0, 0);
                s[1][mt] = __builtin_amdgcn_mfma_f32_16x16x32_f16(kf, qf[1][kb], s[1][mt], 0, 0, 0);
            }
        }
        __builtin_amdgcn_s_setprio(0);

        unsigned pk[2][4][2];
        softmax_upd(s[0], O[0], m[0], l[0], pk[0], g);
        softmax_upd(s[1], O[1], m[1], l[1], pk[1], g);

        // ---- PV: V fragments shared by both q-halves
        const int srcA = ((2 * (g & 1)) << 4) | c;
        const int srcB = ((2 * (g & 1) + 1) << 4) | c;
        const bool hiSel = (g & 2) != 0;
        #pragma unroll
        for (int kb = 0; kb < 2; ++kb) {
            f16x8 vf[8];
            #pragma unroll
            for (int nt = 0; nt < 8; ++nt) {
                const int d  = nt * 16 + c;
                const int gp = ((4 * kb + g) ^ (d & 7)) * 8;
                vf[nt] = *(const f16x8*)&v_s[d * 64 + gp];
            }
            #pragma unroll
            for (int qh = 0; qh < 2; ++qh) {
                unsigned u00 = (unsigned)__shfl((int)pk[qh][2 * kb][0], srcA);
                unsigned u10 = (unsigned)__shfl((int)pk[qh][2 * kb + 1][0], srcA);
                unsigned u01 = (unsigned)__shfl((int)pk[qh][2 * kb][1], srcA);
                unsigned u11 = (unsigned)__shfl((int)pk[qh][2 * kb + 1][1], srcA);
                unsigned u02 = (unsigned)__shfl((int)pk[qh][2 * kb][0], srcB);
                unsigned u12 = (unsigned)__shfl((int)pk[qh][2 * kb + 1][0], srcB);
                unsigned u03 = (unsigned)__shfl((int)pk[qh][2 * kb][1], srcB);
                unsigned u13 = (unsigned)__shfl((int)pk[qh][2 * kb + 1][1], srcB);
                union { unsigned u[4]; f16x8 v; } pa;
                pa.u[0] = hiSel ? u10 : u00;
                pa.u[1] = hiSel ? u11 : u01;
                pa.u[2] = hiSel ? u12 : u02;
                pa.u[3] = hiSel ? u13 : u03;
                __builtin_amdgcn_s_setprio(1);
                #pragma unroll
                for (int nt = 0; nt < 8; ++nt)
                    O[qh][nt] = __builtin_amdgcn_mfma_f32_16x16x32_f16(pa.v, vf[nt], O[qh][nt], 0, 0, 0);
                __builtin_amdgcn_s_setprio(0);
            }
        }
    }

    // ---- epilogue: combine the two paths via LDS
    float il[2][4];
    #pragma unroll
    for (int qh = 0; qh < 2; ++qh)
        #pragma unroll
        for (int r = 0; r < 4; ++r) {
            float L = __shfl(l[qh], (g << 2) | r);
            il[qh][r] = (path ? lam : 1.f) / L;
        }

    __syncthreads();                               // all K/V LDS reads done
    if (path) {
        float* obp = ob + (size_t)(qsub * 32) * 132;
        #pragma unroll
        for (int qh = 0; qh < 2; ++qh)
            #pragma unroll
            for (int nt = 0; nt < 8; ++nt)
                #pragma unroll
                for (int r = 0; r < 4; ++r)
                    obp[(qh * 16 + g * 4 + r) * 132 + nt * 16 + c] = O[qh][nt][r] * il[qh][r];
    }
    __syncthreads();
    if (!path) {
        const float* obp = ob + (size_t)(qsub * 32) * 132;
        const size_t obase = (size_t)(b * T_ + q0) * D_ + h * DH;
        #pragma unroll
        for (int qh = 0; qh < 2; ++qh)
            #pragma unroll
            for (int nt = 0; nt < 8; ++nt)
                #pragma unroll
                for (int r = 0; r < 4; ++r) {
                    float o = O[qh][nt][r] * il[qh][r]
                            - obp[(qh * 16 + g * 4 + r) * 132 + nt * 16 + c];
                    Qh[obase + (size_t)(qh * 16 + g * 4 + r) * D_ + nt * 16 + c] = (_Float16)o;
                }
    }
}

// ---------------------------------------------------------------------------
extern "C" void kernel_launch(void* const* d_in, const int* in_sizes, int n_in,
                              void* d_out, int out_size, void* d_ws, size_t ws_size,
                              hipStream_t stream) {
    const float* x    = (const float*)d_in[0];
    const float* W_q  = (const float*)d_in[1];
    const float* W_k  = (const float*)d_in[2];
    const float* W_v  = (const float*)d_in[3];
    const float* W_o  = (const float*)d_in[4];
    const float* lamp = (const float*)d_in[5];
    float* out = (float*)d_out;

    const size_t PL = (size_t)BT * D_;               // 8.4M elems
    const size_t WL = (size_t)D_ * D_;               // 4.2M elems
    _Float16* Xh = (_Float16*)d_ws;                  // 16 MB
    _Float16* Wq = Xh + PL;                          // 8 MB (recycled for W_o)
    _Float16* Wk = Wq + WL;                          // 8 MB
    _Float16* Wv = Wk + WL;                          // 8 MB
    _Float16* Qh = Wv + WL;                          // 16 MB (attn out alias)
    _Float16* Kh = Qh + PL;                          // 16 MB
    _Float16* Vt = Kh + PL;                          // 16 MB  (total 92.3 MB)
    _Float16* Wo = Wq;                               // dead after Q-GEMM

    // one fused convert launch: x, W_q, W_k, W_v
    dim3 gc((unsigned)(PL / 8 + 255) / 256, 4);
    f32_to_f16_multi<<<gc, 256, 0, stream>>>(x,   Xh, (int)(PL / 8),
                                             W_q, Wq, (int)(WL / 8),
                                             W_k, Wk, (int)(WL / 8),
                                             W_v, Wv, (int)(WL / 8));

    dim3 gg(512);  // (M/128)*(N/128) = 32*16
    gemm16<1><<<gg, 256, 0, stream>>>(Xh, Wq, nullptr, Qh, nullptr, BT, D_, D_);
    gemm16<1><<<gg, 256, 0, stream>>>(Xh, Wk, nullptr, Kh, nullptr, BT, D_, D_);
    gemm16<2><<<gg, 256, 0, stream>>>(Xh, Wv, nullptr, nullptr, Vt, BT, D_, D_);

    f32_to_f16<<<(int)(WL / 8 / 256), 256, 0, stream>>>(W_o, Wo, (int)(WL / 8));

    dim3 ga(T_ / QB, H_, B_);                        // (32, 16, 2) = 1024 blocks
    diff_attn_f16<<<ga, 256, 0, stream>>>(Qh, Kh, Vt, lamp);

    gemm16<0><<<gg, 256, 0, stream>>>(Qh, Wo, out, nullptr, nullptr, BT, D_, D_);
}